// Round 29
// baseline (498.584 us; speedup 1.0000x reference)
//
#include <hip/hip_runtime.h>
#include <hip/hip_bf16.h>

typedef __hip_bfloat16 bf16;

#define Bn    4
#define NCn   3
#define Hn    112
#define Wn    112
#define Cn    128
#define HEADS 4
#define WSn   7
#define SSn   3
#define HDn   32
#define WNt   1024            // total windows = B * 16 * 16
#define Tt    147             // tokens per window = NC * 49
#define SCALE 0.17677669529663687f

#define SA    288
#define SH    1056
#define MT    32              // k_mlp token tile (33.8 KB LDS -> 4 blocks/CU)
#define NROWS 49              // per-channel token count
#define NPAD  64              // padded to 4 M-tiles

static const size_t NE = (size_t)Bn * NCn * Hn * Wn * Cn; // 19,267,584

typedef float f32x4 __attribute__((ext_vector_type(4)));
typedef short s16x8 __attribute__((ext_vector_type(8)));
typedef short s16x4 __attribute__((ext_vector_type(4)));
#define MFMA(a,b,c) __builtin_amdgcn_mfma_f32_16x16x32_bf16((a),(b),(c),0,0,0)

// P (f32 param block) offsets
#define P_QCSA 0
#define P_KCSA 384
#define P_QCCA 768
#define P_KCCA 1152
#define P_VCSA 1536
#define P_BPSA 1664
#define P_VCCA 1792
#define P_BPCA 1920
#define P_B1   2048
#define P_B2   2560
#define P_G1   2688
#define P_N1B  2816
#define P_G2   2944
#define P_N2B  3072
#define P_G3   3200
#define P_N3B  3328

// wT (bf16 packed-fragment weights) offsets, elements
#define W_SAQ 0
#define W_SAK 16384
#define W_SAV 32768
#define W_SAP 49152
#define W_CAQ 65536
#define W_CAK 81920
#define W_CAV 98304
#define W_CAP 114688
#define W_W1T 131072
#define W_W2T 196608

struct Ptrs { const void* p[32]; };

__device__ __forceinline__ float bf2f(bf16 v) { return __bfloat162float(v); }
__device__ __forceinline__ bf16  f2bf(float v) { return __float2bfloat16(v); }
__device__ __forceinline__ short f2bs(float v) { bf16 t = __float2bfloat16(v); return *reinterpret_cast<short*>(&t); }
__device__ __forceinline__ float bs2f(short v) { bf16 t = *reinterpret_cast<bf16*>(&v); return __bfloat162float(t); }

__device__ __forceinline__ float ldi(const void* __restrict__ p, size_t i, int f) {
    return f ? ((const float*)p)[i] : bf2f(((const bf16*)p)[i]);
}

// GELU tanh-form, minimized: x - x*rcp(1 + exp(x*(a + b*x^2)))
__device__ __forceinline__ float gelu(float x) {
    float x2 = x * x;
    float arg = x * fmaf(x2, 0.0713548162f, 1.5957691216f);
    float e = __expf(arg);
    float r = __builtin_amdgcn_rcpf(1.f + e);
    return x - x * r;
}

// Serial in-LDS LN of row at rp (128 bf16), gamma/beta staged in LDS gb[0..255]
__device__ __forceinline__ void ln_inplace(char* __restrict__ rp, const float* __restrict__ gb) {
    float s = 0.f, s2 = 0.f;
    #pragma unroll
    for (int c8 = 0; c8 < 16; ++c8) {
        s16x8 v = *(const s16x8*)(rp + c8 * 16);
        #pragma unroll
        for (int j = 0; j < 8; ++j) { float fv = bs2f(v[j]); s += fv; s2 += fv * fv; }
    }
    float mean = s * (1.f / 128.f);
    float rstd = rsqrtf(s2 * (1.f / 128.f) - mean * mean + 1e-5f);
    #pragma unroll
    for (int c8 = 0; c8 < 16; ++c8) {
        s16x8 v = *(const s16x8*)(rp + c8 * 16);
        #pragma unroll
        for (int j = 0; j < 8; ++j) {
            int col = c8 * 8 + j;
            v[j] = f2bs((bs2f(v[j]) - mean) * rstd * gb[col] + gb[128 + col]);
        }
        *(s16x8*)(rp + c8 * 16) = v;
    }
}

// Parallel LN: 4 consecutive lanes per row (k_mlp)
__device__ __forceinline__ void ln_row4(char* __restrict__ rowbase, const float* __restrict__ gb, int sub) {
    char* rp = rowbase + sub * 64;
    float s = 0.f, s2 = 0.f;
    s16x8 vv[4];
    #pragma unroll
    for (int c = 0; c < 4; ++c) {
        vv[c] = *(const s16x8*)(rp + c * 16);
        #pragma unroll
        for (int j = 0; j < 8; ++j) { float fv = bs2f(vv[c][j]); s += fv; s2 += fv * fv; }
    }
    s  += __shfl_xor(s, 1);  s  += __shfl_xor(s, 2);
    s2 += __shfl_xor(s2, 1); s2 += __shfl_xor(s2, 2);
    float mean = s * (1.f / 128.f);
    float rstd = rsqrtf(s2 * (1.f / 128.f) - mean * mean + 1e-5f);
    #pragma unroll
    for (int c = 0; c < 4; ++c) {
        #pragma unroll
        for (int j = 0; j < 8; ++j) {
            int col = sub * 32 + c * 8 + j;
            vv[c][j] = f2bs((bs2f(vv[c][j]) - mean) * rstd * gb[col] + gb[128 + col]);
        }
        *(s16x8*)(rp + c * 16) = vv[c];
    }
}

// token (wn, t) -> flat spatial row in (B, NC, H, W) layout (after roll by -SS)
__device__ __forceinline__ int tok_row(int wn, int t) {
    int b = wn >> 8, wrem = wn & 255, wi = wrem >> 4, wj = wrem & 15;
    int n = t / 49, p = t % 49, pi = p / 7, pj = p % 7;
    int i = (wi * 7 + pi + SSn) % Hn;
    int j = (wj * 7 + pj + SSn) % Wn;
    return ((b * NCn + n) * Hn + i) * Wn + j;
}

// Detect input dtype (bf16 exponent-band heuristic)
__global__ void k_detect(const unsigned int* __restrict__ xw, int* __restrict__ flag) {
    __shared__ int cnt;
    if (threadIdx.x == 0) cnt = 0;
    __syncthreads();
    int c = 0;
    for (int i = threadIdx.x; i < 8192; i += 256) {
        unsigned e = (xw[i] >> 7) & 0xffu;
        c += (e >= 100u && e <= 140u) ? 1 : 0;
    }
    atomicAdd(&cnt, c);
    __syncthreads();
    if (threadIdx.x == 0) *flag = (cnt < 4096) ? 1 : 0;   // 1 = fp32, 0 = bf16
}

// Merged prep: b0..3 contrast GEMVs (1 matrix/block, LDS-staged vector);
// b4 vectors; b5..68 square W; b69..132 MLP W; b133..164 BM tables.
__global__ __launch_bounds__(256) void k_prep(Ptrs in, const int* __restrict__ dflag,
                                              float* __restrict__ P, bf16* __restrict__ wT,
                                              float* __restrict__ BMT) {
    const int f = *dflag;
    int b = blockIdx.x, tid = threadIdx.x;
    __shared__ float vlds[384];
    if (b < 4) {
        const int wmap[4] = {10, 12, 19, 21};
        const int bmap[4] = {11, 13, 20, 22};
        const int dmap[4] = {P_QCSA, P_KCSA, P_QCCA, P_KCCA};
        const void* vsrc = in.p[b == 3 ? 3 : 2];
        for (int i = tid; i < 384; i += 256) vlds[i] = ldi(vsrc, i, f);
        __syncthreads();
        const void* W = in.p[wmap[b]];
        for (int t = tid; t < 384; t += 256) {
            int n = t >> 7, c = t & 127;
            float acc = 0.f;
            #pragma unroll 4
            for (int d = 0; d < 128; ++d)
                acc += vlds[n * 128 + d] * ldi(W, (size_t)d * 128 + c, f);
            P[dmap[b] + t] = acc + ldi(in.p[bmap[b]], c, f);
        }
    } else if (b == 4) {
        if (tid < 128) {
            P[P_VCSA + tid] = ldi(in.p[15], tid, f);
            P[P_BPSA + tid] = ldi(in.p[17], tid, f);
            P[P_VCCA + tid] = ldi(in.p[24], tid, f);
            P[P_BPCA + tid] = ldi(in.p[26], tid, f);
            P[P_B2   + tid] = ldi(in.p[31], tid, f);
            P[P_G1   + tid] = ldi(in.p[4],  tid, f);
            P[P_N1B  + tid] = ldi(in.p[5],  tid, f);
            P[P_G2   + tid] = ldi(in.p[6],  tid, f);
            P[P_N2B  + tid] = ldi(in.p[7],  tid, f);
            P[P_G3   + tid] = ldi(in.p[8],  tid, f);
            P[P_N3B  + tid] = ldi(in.p[9],  tid, f);
        }
        for (int t = tid; t < 512; t += 256) P[P_B1 + t] = ldi(in.p[29], t, f);
    } else if (b < 69) {
        const int map[8] = {10, 12, 14, 16, 19, 21, 23, 25};
        int unit = (b - 5) * 4 + (tid >> 6), lane = tid & 63;
        int mat = unit >> 5, ntks = unit & 31;
        int ntile = ntks >> 2, ks = ntks & 3;
        int n = ntile * 16 + (lane & 15), k0 = ks * 32 + (lane >> 4) * 8;
        const void* src = in.p[map[mat]];
        s16x8 v;
        #pragma unroll
        for (int j = 0; j < 8; ++j) v[j] = f2bs(ldi(src, (size_t)(k0 + j) * 128 + n, f));
        *(s16x8*)(wT + mat * 16384 + ((size_t)ntks * 64 + lane) * 8) = v;
    } else if (b < 133) {
        int unit = (b - 69) * 4 + (tid >> 6), lane = tid & 63;
        s16x8 v;
        if (unit < 128) {
            int ntile = unit >> 2, ks = unit & 3;
            int n = ntile * 16 + (lane & 15), k0 = ks * 32 + (lane >> 4) * 8;
            #pragma unroll
            for (int j = 0; j < 8; ++j) v[j] = f2bs(ldi(in.p[28], (size_t)(k0 + j) * 512 + n, f));
            *(s16x8*)(wT + W_W1T + ((size_t)unit * 64 + lane) * 8) = v;
        } else {
            int b2 = unit - 128;
            int ntile = b2 >> 4, ks = b2 & 15;
            int n = ntile * 16 + (lane & 15), k0 = ks * 32 + (lane >> 4) * 8;
            #pragma unroll
            for (int j = 0; j < 8; ++j) v[j] = f2bs(ldi(in.p[30], (size_t)(k0 + j) * 128 + n, f));
            *(s16x8*)(wT + W_W2T + ((size_t)b2 * 64 + lane) * 8) = v;
        }
    } else {
        int u = b - 133;
        int stage = u >> 4, pat = (u >> 2) & 3, h = u & 3;
        const void* rpb = in.p[stage ? 27 : 18];
        float* dst = BMT + (size_t)u * 2560;
        int er = pat >> 1, ec = pat & 1;
        for (int i = tid; i < 2560; i += 256) {
            float v = 0.f;
            int qp = i / 52, kp = i - qp * 52;
            if (qp < 49 && kp < 49) {
                int qpi = qp / 7, qpj = qp - qpi * 7, kpi = kp / 7, kpj = kp - kpi * 7;
                float bias = ldi(rpb, ((qpi - kpi + 6) * 13 + (qpj - kpj + 6)) * HEADS + h, f);
                int rq = (er ? (qpi < 4 ? 1 : 2) : 0) * 3 + (ec ? (qpj < 4 ? 1 : 2) : 0);
                int rk = (er ? (kpi < 4 ? 1 : 2) : 0) * 3 + (ec ? (kpj < 4 ? 1 : 2) : 0);
                v = bias + (rq == rk ? 0.f : -100.f);
            }
            dst[i] = v;
        }
    }
}

// SA (per-channel tile, 49 rows): gather x (persist bf16 to xr) -> LN1 -> Q/K/V GEMM
__global__ __launch_bounds__(256) void k_qkv_sa(
    const void* __restrict__ x, bf16* __restrict__ xr,
    const float* __restrict__ P, const bf16* __restrict__ wT,
    const int* __restrict__ dflag,
    bf16* __restrict__ tokQ, bf16* __restrict__ tokK, bf16* __restrict__ tokV) {
    const int f = *dflag;
    __shared__ char ldsA[NPAD * SA];
    __shared__ int rowIdx[NROWS];
    __shared__ float gb[256];
    int wn = blockIdx.x, nc = blockIdx.y, tid = threadIdx.x;
    int t0 = nc * NROWS;
    if (tid < NROWS) rowIdx[tid] = tok_row(wn, t0 + tid);
    gb[tid] = tid < 128 ? P[P_G1 + tid] : P[P_N1B + tid - 128];
    for (int i = tid; i < 15 * SA / 4; i += 256) ((int*)(ldsA + NROWS * SA))[i] = 0;
    __syncthreads();
    for (int idx = tid; idx < NROWS * 16; idx += 256) {
        int t = idx >> 4, c8 = idx & 15;
        size_t g = (size_t)rowIdx[t] * Cn + c8 * 8;
        s16x8 v;
        if (f) {
            const float* s = (const float*)x + g;
            #pragma unroll
            for (int j = 0; j < 8; ++j) v[j] = f2bs(s[j]);
        } else {
            v = *(const s16x8*)((const bf16*)x + g);
        }
        *(s16x8*)(ldsA + t * SA + c8 * 16) = v;
        *(s16x8*)(xr + g) = v;
    }
    __syncthreads();
    if (tid < NROWS) ln_inplace(ldsA + tid * SA, gb);
    __syncthreads();
    int wv = tid >> 6, lane = tid & 63, l15 = lane & 15, lg = lane >> 4;
    #pragma unroll 1
    for (int mat = 0; mat < 3; ++mat) {
        const bf16* W = wT + mat * 16384;
        bf16* dst = mat == 0 ? tokQ : (mat == 1 ? tokK : tokV);
        #pragma unroll 1
        for (int ni = 0; ni < 2; ++ni) {
            int nt = wv * 2 + ni;
            f32x4 acc[4] = {};
            #pragma unroll
            for (int ks = 0; ks < 4; ++ks) {
                s16x8 bfrag = *(const s16x8*)(W + (((nt << 2) + ks) * 64 + lane) * 8);
                #pragma unroll
                for (int mt = 0; mt < 4; ++mt) {
                    s16x8 af = *(const s16x8*)(ldsA + (mt * 16 + l15) * SA + ks * 64 + lg * 16);
                    acc[mt] = MFMA(bfrag, af, acc[mt]);
                }
            }
            int col0 = nt * 16 + lg * 4;
            #pragma unroll
            for (int mt = 0; mt < 4; ++mt) {
                int tl = mt * 16 + l15;
                if (tl < NROWS) {
                    int t = t0 + tl;
                    s16x4 pk;
                    if (mat == 0) {
                        f32x4 b4 = *(const f32x4*)(P + P_QCSA + nc * 128 + col0);
                        #pragma unroll
                        for (int r = 0; r < 4; ++r) pk[r] = f2bs((acc[mt][r] + b4[r]) * SCALE);
                    } else if (mat == 1) {
                        f32x4 b4 = *(const f32x4*)(P + P_KCSA + nc * 128 + col0);
                        #pragma unroll
                        for (int r = 0; r < 4; ++r) pk[r] = f2bs(acc[mt][r] + b4[r]);
                    } else {
                        f32x4 b4 = *(const f32x4*)(P + P_VCSA + col0);
                        #pragma unroll
                        for (int r = 0; r < 4; ++r) pk[r] = f2bs(acc[mt][r] + b4[r]);
                    }
                    *(s16x4*)(dst + ((size_t)wn * Tt + t) * Cn + col0) = pk;
                }
            }
        }
    }
}

// MFMA attention (4-wave): no-max softmax (scores |s|<~1 by construction;
// mask -100 -> exp flushes to 0); BM staged from precomputed f32 tables
__global__ __launch_bounds__(256) void k_attn(
    const bf16* __restrict__ Q, const bf16* __restrict__ K, const bf16* __restrict__ V,
    bf16* __restrict__ O, const float* __restrict__ BMbase) {
    __shared__ char ldsK[40 * 256];
    __shared__ char ldsV[32 * 336];
    __shared__ char ldsP[4 * 16 * 336];
    __shared__ float BM[2560];
    __shared__ float lArr[4][16];
    int wn = blockIdx.x, h = blockIdx.y, tid = threadIdx.x;
    int wi = (wn >> 4) & 15, wj = wn & 15;
    size_t base = (size_t)wn * Tt * Cn + h * HDn;
    for (int idx = tid; idx < 640; idx += 256) {
        int key = idx >> 2, ch = idx & 3;
        s16x8 kv = {}, vv = {};
        if (key < Tt) {
            kv = *(const s16x8*)(K + base + (size_t)key * Cn + ch * 8);
            vv = *(const s16x8*)(V + base + (size_t)key * Cn + ch * 8);
        }
        *(s16x8*)(ldsK + (key >> 2) * 256 + (key & 3) * 64 + ch * 16) = kv;
        #pragma unroll
        for (int j = 0; j < 8; ++j)
            *(short*)(ldsV + (ch * 8 + j) * 336 + key * 2) = vv[j];
    }
    {
        int pat = ((wi == 15) << 1) | (wj == 15);
        const f32x4* src = (const f32x4*)(BMbase + (size_t)(pat * 4 + h) * 2560);
        f32x4* dst4 = (f32x4*)BM;
        for (int i = tid; i < 640; i += 256) dst4[i] = src[i];
    }
    __syncthreads();
    int wv = tid >> 6, lane = tid & 63, l15 = lane & 15, lg = lane >> 4;
    char* myP = ldsP + wv * (16 * 336);
    int kpA[10];
    #pragma unroll
    for (int nt = 0; nt < 10; ++nt) {
        int key = nt * 16 + l15;
        kpA[nt] = key - (key >= 147 ? 147 : (key >= 98 ? 98 : (key >= 49 ? 49 : 0)));
    }
    for (int mt = wv; mt < 10; mt += 4) {
        int qrow = mt * 16 + l15; if (qrow > 146) qrow = 146;
        s16x8 qf = *(const s16x8*)(Q + base + (size_t)qrow * Cn + lg * 8);
        f32x4 acc[10];
        #pragma unroll
        for (int nt = 0; nt < 10; ++nt) {
            int key = nt * 16 + l15;
            s16x8 bfrag = *(const s16x8*)(ldsK + (key >> 2) * 256 + (key & 3) * 64 + lg * 16);
            f32x4 z = {};
            acc[nt] = MFMA(qf, bfrag, z);
        }
        float linv[4];
        #pragma unroll
        for (int r = 0; r < 4; ++r) {
            int row = mt * 16 + lg * 4 + r;
            int qp = row - (row >= 147 ? 147 : (row >= 98 ? 98 : (row >= 49 ? 49 : 0)));
            float l = 0.f;
            #pragma unroll
            for (int nt = 0; nt < 10; ++nt) {
                float p = (nt == 9 && l15 >= 3) ? 0.f
                        : __expf(acc[nt][r] + BM[qp * 52 + kpA[nt]]);
                l += p;
                *(bf16*)(myP + (lg * 4 + r) * 336 + (nt * 16 + l15) * 2) = f2bf(p);
            }
            #pragma unroll
            for (int off = 1; off < 16; off <<= 1) l += __shfl_xor(l, off);
            linv[r] = 1.f / l;
        }
        if (l15 == 0) {
            #pragma unroll
            for (int r = 0; r < 4; ++r) lArr[wv][lg * 4 + r] = linv[r];
        }
        float myinv = lArr[wv][l15];
        #pragma unroll
        for (int ntv = 0; ntv < 2; ++ntv) {
            f32x4 ao = {};
            #pragma unroll
            for (int ks = 0; ks < 5; ++ks) {
                s16x8 af = *(const s16x8*)(myP + l15 * 336 + ks * 64 + lg * 16);
                s16x8 vf = *(const s16x8*)(ldsV + (ntv * 16 + l15) * 336 + ks * 64 + lg * 16);
                ao = MFMA(vf, af, ao);
            }
            int q = mt * 16 + l15;
            if (q < Tt) {
                s16x4 pk;
                #pragma unroll
                for (int r = 0; r < 4; ++r) pk[r] = f2bs(ao[r] * myinv);
                *(s16x4*)(O + base + (size_t)q * Cn + ntv * 16 + lg * 4) = pk;
            }
        }
    }
}

// CA output projection (per-channel tile): reg accumulators + early xr prefetch
__global__ __launch_bounds__(256) void k_proj(
    const bf16* __restrict__ tokO, const float* __restrict__ P, const bf16* __restrict__ W,
    int bpOff, bf16* __restrict__ xr) {
    __shared__ char ldsA[NPAD * SA];
    __shared__ int rowIdx[NROWS];
    int wn = blockIdx.x, nc = blockIdx.y, tid = threadIdx.x;
    int t0 = nc * NROWS;
    if (tid < NROWS) rowIdx[tid] = tok_row(wn, t0 + tid);
    for (int i = tid; i < 15 * SA / 4; i += 256) ((int*)(ldsA + NROWS * SA))[i] = 0;
    __syncthreads();
    int wv = tid >> 6, lane = tid & 63, l15 = lane & 15, lg = lane >> 4;
    s16x4 xrc[2][4];
    #pragma unroll
    for (int ni = 0; ni < 2; ++ni) {
        int col0 = (wv * 2 + ni) * 16 + lg * 4;
        #pragma unroll
        for (int mt = 0; mt < 4; ++mt) {
            int tl = mt * 16 + l15;
            int rr = rowIdx[tl < NROWS ? tl : 0];
            xrc[ni][mt] = *(const s16x4*)(xr + (size_t)rr * Cn + col0);
        }
    }
    for (int idx = tid; idx < NROWS * 16; idx += 256) {
        int t = idx >> 4, c8 = idx & 15;
        s16x8 v = *(const s16x8*)(tokO + ((size_t)wn * Tt + t0 + t) * Cn + c8 * 8);
        *(s16x8*)(ldsA + t * SA + c8 * 16) = v;
    }
    __syncthreads();
    f32x4 acc2[2][4] = {};
    #pragma unroll
    for (int ni = 0; ni < 2; ++ni) {
        int nt = wv * 2 + ni;
        #pragma unroll
        for (int ks = 0; ks < 4; ++ks) {
            s16x8 bfrag = *(const s16x8*)(W + (((nt << 2) + ks) * 64 + lane) * 8);
            #pragma unroll
            for (int mt = 0; mt < 4; ++mt) {
                s16x8 af = *(const s16x8*)(ldsA + (mt * 16 + l15) * SA + ks * 64 + lg * 16);
                acc2[ni][mt] = MFMA(bfrag, af, acc2[ni][mt]);
            }
        }
    }
    #pragma unroll
    for (int ni = 0; ni < 2; ++ni) {
        int col0 = (wv * 2 + ni) * 16 + lg * 4;
        f32x4 bp4 = *(const f32x4*)(P + bpOff + col0);
        #pragma unroll
        for (int mt = 0; mt < 4; ++mt) {
            int tl = mt * 16 + l15;
            if (tl < NROWS) {
                s16x4 pk;
                #pragma unroll
                for (int r = 0; r < 4; ++r) pk[r] = f2bs(bs2f(xrc[ni][mt][r]) + acc2[ni][mt][r] + bp4[r]);
                *(s16x4*)(xr + (size_t)rowIdx[tl] * Cn + col0) = pk;
            }
        }
    }
}

// Fused SA-proj + residual + LN2 + CA Q/K/V (per-channel tile)
__global__ __launch_bounds__(256) void k_proj_ca(
    const bf16* __restrict__ tokO, const float* __restrict__ P, const bf16* __restrict__ wT,
    const void* __restrict__ xkv, const int* __restrict__ dflag, bf16* __restrict__ xr,
    bf16* __restrict__ tokQ, bf16* __restrict__ tokK, bf16* __restrict__ tokV) {
    const int f = *dflag;
    __shared__ char ldsA[NPAD * SA];
    __shared__ int rowIdx[NROWS];
    __shared__ float gb[256];
    int wn = blockIdx.x, nc = blockIdx.y, tid = threadIdx.x;
    int t0 = nc * NROWS;
    if (tid < NROWS) rowIdx[tid] = tok_row(wn, t0 + tid);
    gb[tid] = tid < 128 ? P[P_G2 + tid] : P[P_N2B + tid - 128];
    for (int i = tid; i < 15 * SA / 4; i += 256) ((int*)(ldsA + NROWS * SA))[i] = 0;
    __syncthreads();
    for (int idx = tid; idx < NROWS * 16; idx += 256) {
        int t = idx >> 4, c8 = idx & 15;
        s16x8 v = *(const s16x8*)(tokO + ((size_t)wn * Tt + t0 + t) * Cn + c8 * 8);
        *(s16x8*)(ldsA + t * SA + c8 * 16) = v;
    }
    __syncthreads();
    int wv = tid >> 6, lane = tid & 63, l15 = lane & 15, lg = lane >> 4;
    {
        const bf16* W = wT + W_SAP;
        #pragma unroll 1
        for (int ni = 0; ni < 2; ++ni) {
            int nt = wv * 2 + ni;
            f32x4 acc[4] = {};
            #pragma unroll
            for (int ks = 0; ks < 4; ++ks) {
                s16x8 bfrag = *(const s16x8*)(W + (((nt << 2) + ks) * 64 + lane) * 8);
                #pragma unroll
                for (int mt = 0; mt < 4; ++mt) {
                    s16x8 af = *(const s16x8*)(ldsA + (mt * 16 + l15) * SA + ks * 64 + lg * 16);
                    acc[mt] = MFMA(bfrag, af, acc[mt]);
                }
            }
            int col0 = nt * 16 + lg * 4;
            f32x4 bp4 = *(const f32x4*)(P + P_BPSA + col0);
            #pragma unroll
            for (int mt = 0; mt < 4; ++mt) {
                int tl = mt * 16 + l15;
                if (tl < NROWS) {
                    size_t o = (size_t)rowIdx[tl] * Cn + col0;
                    s16x4 cur = *(const s16x4*)(xr + o);
                    s16x4 pk;
                    #pragma unroll
                    for (int r = 0; r < 4; ++r) pk[r] = f2bs(bs2f(cur[r]) + acc[mt][r] + bp4[r]);
                    *(s16x4*)(xr + o) = pk;
                }
            }
        }
    }
    __syncthreads();
    for (int idx = tid; idx < NROWS * 16; idx += 256) {
        int t = idx >> 4, c8 = idx & 15;
        s16x8 v = *(const s16x8*)(xr + (size_t)rowIdx[t] * Cn + c8 * 8);
        *(s16x8*)(ldsA + t * SA + c8 * 16) = v;
    }
    __syncthreads();
    if (tid < NROWS) ln_inplace(ldsA + tid * SA, gb);
    __syncthreads();
    {
        const bf16* W = wT + W_CAQ;
        #pragma unroll 1
        for (int ni = 0; ni < 2; ++ni) {
            int nt = wv * 2 + ni;
            f32x4 acc[4] = {};
            #pragma unroll
            for (int ks = 0; ks < 4; ++ks) {
                s16x8 bfrag = *(const s16x8*)(W + (((nt << 2) + ks) * 64 + lane) * 8);
                #pragma unroll
                for (int mt = 0; mt < 4; ++mt) {
                    s16x8 af = *(const s16x8*)(ldsA + (mt * 16 + l15) * SA + ks * 64 + lg * 16);
                    acc[mt] = MFMA(bfrag, af, acc[mt]);
                }
            }
            int col0 = nt * 16 + lg * 4;
            #pragma unroll
            for (int mt = 0; mt < 4; ++mt) {
                int tl = mt * 16 + l15;
                if (tl < NROWS) {
                    int t = t0 + tl;
                    f32x4 b4 = *(const f32x4*)(P + P_QCCA + nc * 128 + col0);
                    s16x4 pk;
                    #pragma unroll
                    for (int r = 0; r < 4; ++r) pk[r] = f2bs((acc[mt][r] + b4[r]) * SCALE);
                    *(s16x4*)(tokQ + ((size_t)wn * Tt + t) * Cn + col0) = pk;
                }
            }
        }
    }
    __syncthreads();
    for (int idx = tid; idx < NROWS * 16; idx += 256) {
        int t = idx >> 4, c8 = idx & 15;
        s16x8 v;
        if (f) {
            const float* s = (const float*)xkv + (size_t)rowIdx[t] * Cn + c8 * 8;
            #pragma unroll
            for (int j = 0; j < 8; ++j) v[j] = f2bs(s[j]);
        } else {
            v = *(const s16x8*)((const bf16*)xkv + (size_t)rowIdx[t] * Cn + c8 * 8);
        }
        *(s16x8*)(ldsA + t * SA + c8 * 16) = v;
    }
    __syncthreads();
    #pragma unroll 1
    for (int mat = 0; mat < 2; ++mat) {
        const bf16* W = wT + (mat == 0 ? W_CAK : W_CAV);
        bf16* dst = mat == 0 ? tokK : tokV;
        #pragma unroll 1
        for (int ni = 0; ni < 2; ++ni) {
            int nt = wv * 2 + ni;
            f32x4 acc[4] = {};
            #pragma unroll
            for (int ks = 0; ks < 4; ++ks) {
                s16x8 bfrag = *(const s16x8*)(W + (((nt << 2) + ks) * 64 + lane) * 8);
                #pragma unroll
                for (int mt = 0; mt < 4; ++mt) {
                    s16x8 af = *(const s16x8*)(ldsA + (mt * 16 + l15) * SA + ks * 64 + lg * 16);
                    acc[mt] = MFMA(bfrag, af, acc[mt]);
                }
            }
            int col0 = nt * 16 + lg * 4;
            #pragma unroll
            for (int mt = 0; mt < 4; ++mt) {
                int tl = mt * 16 + l15;
                if (tl < NROWS) {
                    int t = t0 + tl;
                    f32x4 b4 = (mat == 0) ? *(const f32x4*)(P + P_KCCA + nc * 128 + col0)
                                          : *(const f32x4*)(P + P_VCCA + col0);
                    s16x4 pk;
                    #pragma unroll
                    for (int r = 0; r < 4; ++r) pk[r] = f2bs(acc[mt][r] + b4[r]);
                    *(s16x4*)(dst + ((size_t)wn * Tt + t) * Cn + col0) = pk;
                }
            }
        }
    }
}

// Fused LN3 + MLP: 32-token tile (33.8 KB LDS -> 4 blocks/CU), aliased LDS, rcp-GELU
__global__ __launch_bounds__(256) void k_mlp(
    const bf16* __restrict__ xr, const float* __restrict__ P, const bf16* __restrict__ wT,
    const int* __restrict__ dflag, void* __restrict__ outp) {
    __shared__ char ldsU[MT * SH];
    __shared__ float gb[256];
    char* ldsA = ldsU;
    char* ldsH = ldsU;
    int tid = threadIdx.x;
    size_t t0 = (size_t)blockIdx.x * MT;
    gb[tid] = tid < 128 ? P[P_G3 + tid] : P[P_N3B + tid - 128];
    __syncthreads();
    for (int idx = tid; idx < MT * 16; idx += 256) {
        int t = idx >> 4, c8 = idx & 15;
        s16x8 v = *(const s16x8*)(xr + (t0 + t) * Cn + c8 * 8);
        *(s16x8*)(ldsA + t * SA + c8 * 16) = v;
    }
    __syncthreads();
    {
        int row = tid >> 3, sub = tid & 7;
        if (sub < 4) ln_row4(ldsA + row * SA, gb, sub);
    }
    __syncthreads();
    int wv = tid >> 6, lane = tid & 63, l15 = lane & 15, lg = lane >> 4;
    const bf16* W1 = wT + W_W1T;
    s16x8 a[2][4];
    #pragma unroll
    for (int m = 0; m < 2; ++m)
        #pragma unroll
        for (int ks = 0; ks < 4; ++ks)
            a[m][ks] = *(const s16x8*)(ldsA + (m * 16 + l15) * SA + ks * 64 + lg * 16);
    __syncthreads();
    {
        int nt0 = wv * 8;
        s16x8 bc0 = *(const s16x8*)(W1 + (((nt0 << 2) + 0) * 64 + lane) * 8);
        s16x8 bc1 = *(const s16x8*)(W1 + (((nt0 << 2) + 1) * 64 + lane) * 8);
        s16x8 bc2 = *(const s16x8*)(W1 + (((nt0 << 2) + 2) * 64 + lane) * 8);
        s16x8 bc3 = *(const s16x8*)(W1 + (((nt0 << 2) + 3) * 64 + lane) * 8);
        #pragma unroll 1
        for (int ni = 0; ni < 8; ++ni) {
            int nt = nt0 + ni;
            s16x8 bn0 = *(const s16x8*)(W1 + ((((nt + 1) << 2) + 0) * 64 + lane) * 8);
            s16x8 bn1 = *(const s16x8*)(W1 + ((((nt + 1) << 2) + 1) * 64 + lane) * 8);
            s16x8 bn2 = *(const s16x8*)(W1 + ((((nt + 1) << 2) + 2) * 64 + lane) * 8);
            s16x8 bn3 = *(const s16x8*)(W1 + ((((nt + 1) << 2) + 3) * 64 + lane) * 8);
            f32x4 acc[2] = {};
            #pragma unroll
            for (int m = 0; m < 2; ++m) {
                acc[m] = MFMA(bc0, a[m][0], acc[m]);
                acc[m] = MFMA(bc1, a[m][1], acc[m]);
                acc[m] = MFMA(bc2, a[m][2], acc[m]);
                acc[m] = MFMA(bc3, a[m][3], acc[m]);
            }
            int col0 = nt * 16 + lg * 4;
            f32x4 b14 = *(const f32x4*)(P + P_B1 + col0);
            #pragma unroll
            for (int m = 0; m < 2; ++m) {
                s16x4 pk;
                #pragma unroll
                for (int r = 0; r < 4; ++r) pk[r] = f2bs(gelu(acc[m][r] + b14[r]));
                *(s16x4*)(ldsH + (m * 16 + l15) * SH + col0 * 2) = pk;
            }
            bc0 = bn0; bc1 = bn1; bc2 = bn2; bc3 = bn3;
        }
    }
    __syncthreads();
    const int f = *dflag;
    const bf16* W2 = wT + W_W2T;
    #pragma unroll 1
    for (int ni = 0; ni < 2; ++ni) {
        int nt = wv * 2 + ni;
        f32x4 acc[2] = {};
        s16x8 bc = *(const s16x8*)(W2 + (((nt << 4) + 0) * 64 + lane) * 8);
        #pragma unroll 1
        for (int ks = 0; ks < 16; ++ks) {
            s16x8 bn = *(const s16x8*)(W2 + (((nt << 4) + ks + 1) * 64 + lane) * 8);
            #pragma unroll
            for (int m = 0; m < 2; ++m) {
                s16x8 af = *(const s16x8*)(ldsH + (m * 16 + l15) * SH + ks * 64 + lg * 16);
                acc[m] = MFMA(bc, af, acc[m]);
            }
            bc = bn;
        }
        int col0 = nt * 16 + lg * 4;
        f32x4 b24 = *(const f32x4*)(P + P_B2 + col0);
        #pragma unroll
        for (int m = 0; m < 2; ++m) {
            size_t g = (t0 + m * 16 + l15) * Cn + col0;
            s16x4 cur = *(const s16x4*)(xr + g);
            if (f) {
                f32x4 o;
                #pragma unroll
                for (int r = 0; r < 4; ++r) o[r] = bs2f(cur[r]) + acc[m][r] + b24[r];
                *(f32x4*)((float*)outp + g) = o;
            } else {
                s16x4 pk;
                #pragma unroll
                for (int r = 0; r < 4; ++r) pk[r] = f2bs(bs2f(cur[r]) + acc[m][r] + b24[r]);
                *(s16x4*)((bf16*)outp + g) = pk;
            }
        }
    }
}

extern "C" void kernel_launch(void* const* d_in, const int* in_sizes, int n_in,
                              void* d_out, int out_size, void* d_ws, size_t ws_size,
                              hipStream_t stream) {
    Ptrs ptrs;
    for (int i = 0; i < 32; ++i) ptrs.p[i] = d_in[i];

    char* base = (char*)d_ws;
    float* P    = (float*)base;                   // 8192 f32 = 32 KB
    int*  dflag = (int*)(base + 32768);
    bf16* wT    = (bf16*)(base + 33024);          // 262144 bf16 = 512 KB
    float* BMT  = (float*)(wT + 262144);          // 32 * 2560 f32 = 327.7 KB
    bf16* xr    = (bf16*)(BMT + 81920);           // NE bf16 residual
    bf16* tokK  = xr + NE;
    bf16* tokV  = tokK + NE;
    bf16* tokQ  = (bf16*)d_out;                   // Q and O alias in d_out

    k_detect<<<1, 256, 0, stream>>>((const unsigned int*)d_in[0], dflag);
    k_prep<<<165, 256, 0, stream>>>(ptrs, dflag, P, wT, BMT);
    // ---- self-attention stage (also materializes xr = bf16(x)) ----
    k_qkv_sa<<<dim3(WNt, 3), 256, 0, stream>>>(d_in[0], xr, P, wT, dflag, tokQ, tokK, tokV);
    k_attn<<<dim3(WNt, HEADS), 256, 0, stream>>>(tokQ, tokK, tokV, tokQ, BMT);
    // ---- fused SA-proj + CA-qkv ----
    k_proj_ca<<<dim3(WNt, 3), 256, 0, stream>>>(tokQ, P, wT, d_in[1], dflag, xr, tokQ, tokK, tokV);
    // ---- cross-attention ----
    k_attn<<<dim3(WNt, HEADS), 256, 0, stream>>>(tokQ, tokK, tokV, tokQ, BMT + 16 * 2560);
    k_proj<<<dim3(WNt, 3), 256, 0, stream>>>(tokQ, P, wT + W_CAP, P_BPCA, xr);
    // ---- MLP stage ----
    k_mlp<<<(int)(NE / Cn / MT), 256, 0, stream>>>(xr, P, wT, dflag, d_out);
}

// Round 30
// 492.166 us; speedup vs baseline: 1.0130x; 1.0130x over previous
//
#include <hip/hip_runtime.h>
#include <hip/hip_bf16.h>

typedef __hip_bfloat16 bf16;

#define Bn    4
#define NCn   3
#define Hn    112
#define Wn    112
#define Cn    128
#define HEADS 4
#define WSn   7
#define SSn   3
#define HDn   32
#define WNt   1024            // total windows = B * 16 * 16
#define Tt    147             // tokens per window = NC * 49
#define SCALE 0.17677669529663687f
#define SCALE2 0.25503582280462527f   // SCALE * log2(e)
#define LOG2E 1.4426950408889634f

#define SA    288
#define SH    1056
#define MT    32              // k_mlp token tile (33.8 KB LDS -> 4 blocks/CU)
#define NROWS 49              // per-channel token count
#define NPAD  64              // padded to 4 M-tiles

static const size_t NE = (size_t)Bn * NCn * Hn * Wn * Cn; // 19,267,584

typedef float f32x4 __attribute__((ext_vector_type(4)));
typedef short s16x8 __attribute__((ext_vector_type(8)));
typedef short s16x4 __attribute__((ext_vector_type(4)));
#define MFMA(a,b,c) __builtin_amdgcn_mfma_f32_16x16x32_bf16((a),(b),(c),0,0,0)

// P (f32 param block) offsets
#define P_QCSA 0
#define P_KCSA 384
#define P_QCCA 768
#define P_KCCA 1152
#define P_VCSA 1536
#define P_BPSA 1664
#define P_VCCA 1792
#define P_BPCA 1920
#define P_B1   2048
#define P_B2   2560
#define P_G1   2688
#define P_N1B  2816
#define P_G2   2944
#define P_N2B  3072
#define P_G3   3200
#define P_N3B  3328

// wT (bf16 packed-fragment weights) offsets, elements
#define W_SAQ 0
#define W_SAK 16384
#define W_SAV 32768
#define W_SAP 49152
#define W_CAQ 65536
#define W_CAK 81920
#define W_CAV 98304
#define W_CAP 114688
#define W_W1T 131072
#define W_W2T 196608

struct Ptrs { const void* p[32]; };

__device__ __forceinline__ float bf2f(bf16 v) { return __bfloat162float(v); }
__device__ __forceinline__ bf16  f2bf(float v) { return __float2bfloat16(v); }
__device__ __forceinline__ short f2bs(float v) { bf16 t = __float2bfloat16(v); return *reinterpret_cast<short*>(&t); }
__device__ __forceinline__ float bs2f(short v) { bf16 t = *reinterpret_cast<bf16*>(&v); return __bfloat162float(t); }

__device__ __forceinline__ float ldi(const void* __restrict__ p, size_t i, int f) {
    return f ? ((const float*)p)[i] : bf2f(((const bf16*)p)[i]);
}

// GELU tanh-form, minimized: x - x*rcp(1 + exp(x*(a + b*x^2)))
__device__ __forceinline__ float gelu(float x) {
    float x2 = x * x;
    float arg = x * fmaf(x2, 0.0713548162f, 1.5957691216f);
    float e = __expf(arg);
    float r = __builtin_amdgcn_rcpf(1.f + e);
    return x - x * r;
}

// Serial in-LDS LN of row at rp (128 bf16), gamma/beta staged in LDS gb[0..255]
__device__ __forceinline__ void ln_inplace(char* __restrict__ rp, const float* __restrict__ gb) {
    float s = 0.f, s2 = 0.f;
    #pragma unroll
    for (int c8 = 0; c8 < 16; ++c8) {
        s16x8 v = *(const s16x8*)(rp + c8 * 16);
        #pragma unroll
        for (int j = 0; j < 8; ++j) { float fv = bs2f(v[j]); s += fv; s2 += fv * fv; }
    }
    float mean = s * (1.f / 128.f);
    float rstd = rsqrtf(s2 * (1.f / 128.f) - mean * mean + 1e-5f);
    #pragma unroll
    for (int c8 = 0; c8 < 16; ++c8) {
        s16x8 v = *(const s16x8*)(rp + c8 * 16);
        #pragma unroll
        for (int j = 0; j < 8; ++j) {
            int col = c8 * 8 + j;
            v[j] = f2bs((bs2f(v[j]) - mean) * rstd * gb[col] + gb[128 + col]);
        }
        *(s16x8*)(rp + c8 * 16) = v;
    }
}

// Parallel LN: 4 consecutive lanes per row (k_mlp)
__device__ __forceinline__ void ln_row4(char* __restrict__ rowbase, const float* __restrict__ gb, int sub) {
    char* rp = rowbase + sub * 64;
    float s = 0.f, s2 = 0.f;
    s16x8 vv[4];
    #pragma unroll
    for (int c = 0; c < 4; ++c) {
        vv[c] = *(const s16x8*)(rp + c * 16);
        #pragma unroll
        for (int j = 0; j < 8; ++j) { float fv = bs2f(vv[c][j]); s += fv; s2 += fv * fv; }
    }
    s  += __shfl_xor(s, 1);  s  += __shfl_xor(s, 2);
    s2 += __shfl_xor(s2, 1); s2 += __shfl_xor(s2, 2);
    float mean = s * (1.f / 128.f);
    float rstd = rsqrtf(s2 * (1.f / 128.f) - mean * mean + 1e-5f);
    #pragma unroll
    for (int c = 0; c < 4; ++c) {
        #pragma unroll
        for (int j = 0; j < 8; ++j) {
            int col = sub * 32 + c * 8 + j;
            vv[c][j] = f2bs((bs2f(vv[c][j]) - mean) * rstd * gb[col] + gb[128 + col]);
        }
        *(s16x8*)(rp + c * 16) = vv[c];
    }
}

// token (wn, t) -> flat spatial row in (B, NC, H, W) layout (after roll by -SS)
__device__ __forceinline__ int tok_row(int wn, int t) {
    int b = wn >> 8, wrem = wn & 255, wi = wrem >> 4, wj = wrem & 15;
    int n = t / 49, p = t % 49, pi = p / 7, pj = p % 7;
    int i = (wi * 7 + pi + SSn) % Hn;
    int j = (wj * 7 + pj + SSn) % Wn;
    return ((b * NCn + n) * Hn + i) * Wn + j;
}

// Detect input dtype (bf16 exponent-band heuristic)
__global__ void k_detect(const unsigned int* __restrict__ xw, int* __restrict__ flag) {
    __shared__ int cnt;
    if (threadIdx.x == 0) cnt = 0;
    __syncthreads();
    int c = 0;
    for (int i = threadIdx.x; i < 8192; i += 256) {
        unsigned e = (xw[i] >> 7) & 0xffu;
        c += (e >= 100u && e <= 140u) ? 1 : 0;
    }
    atomicAdd(&cnt, c);
    __syncthreads();
    if (threadIdx.x == 0) *flag = (cnt < 4096) ? 1 : 0;   // 1 = fp32, 0 = bf16
}

// Merged prep: b0..3 contrast GEMVs (1 matrix/block, LDS-staged vector);
// b4 vectors; b5..68 square W; b69..132 MLP W; b133..164 BM tables (pre-scaled by log2e).
__global__ __launch_bounds__(256) void k_prep(Ptrs in, const int* __restrict__ dflag,
                                              float* __restrict__ P, bf16* __restrict__ wT,
                                              float* __restrict__ BMT) {
    const int f = *dflag;
    int b = blockIdx.x, tid = threadIdx.x;
    __shared__ float vlds[384];
    if (b < 4) {
        const int wmap[4] = {10, 12, 19, 21};
        const int bmap[4] = {11, 13, 20, 22};
        const int dmap[4] = {P_QCSA, P_KCSA, P_QCCA, P_KCCA};
        const void* vsrc = in.p[b == 3 ? 3 : 2];
        for (int i = tid; i < 384; i += 256) vlds[i] = ldi(vsrc, i, f);
        __syncthreads();
        const void* W = in.p[wmap[b]];
        for (int t = tid; t < 384; t += 256) {
            int n = t >> 7, c = t & 127;
            float acc = 0.f;
            #pragma unroll 4
            for (int d = 0; d < 128; ++d)
                acc += vlds[n * 128 + d] * ldi(W, (size_t)d * 128 + c, f);
            P[dmap[b] + t] = acc + ldi(in.p[bmap[b]], c, f);
        }
    } else if (b == 4) {
        if (tid < 128) {
            P[P_VCSA + tid] = ldi(in.p[15], tid, f);
            P[P_BPSA + tid] = ldi(in.p[17], tid, f);
            P[P_VCCA + tid] = ldi(in.p[24], tid, f);
            P[P_BPCA + tid] = ldi(in.p[26], tid, f);
            P[P_B2   + tid] = ldi(in.p[31], tid, f);
            P[P_G1   + tid] = ldi(in.p[4],  tid, f);
            P[P_N1B  + tid] = ldi(in.p[5],  tid, f);
            P[P_G2   + tid] = ldi(in.p[6],  tid, f);
            P[P_N2B  + tid] = ldi(in.p[7],  tid, f);
            P[P_G3   + tid] = ldi(in.p[8],  tid, f);
            P[P_N3B  + tid] = ldi(in.p[9],  tid, f);
        }
        for (int t = tid; t < 512; t += 256) P[P_B1 + t] = ldi(in.p[29], t, f);
    } else if (b < 69) {
        const int map[8] = {10, 12, 14, 16, 19, 21, 23, 25};
        int unit = (b - 5) * 4 + (tid >> 6), lane = tid & 63;
        int mat = unit >> 5, ntks = unit & 31;
        int ntile = ntks >> 2, ks = ntks & 3;
        int n = ntile * 16 + (lane & 15), k0 = ks * 32 + (lane >> 4) * 8;
        const void* src = in.p[map[mat]];
        s16x8 v;
        #pragma unroll
        for (int j = 0; j < 8; ++j) v[j] = f2bs(ldi(src, (size_t)(k0 + j) * 128 + n, f));
        *(s16x8*)(wT + mat * 16384 + ((size_t)ntks * 64 + lane) * 8) = v;
    } else if (b < 133) {
        int unit = (b - 69) * 4 + (tid >> 6), lane = tid & 63;
        s16x8 v;
        if (unit < 128) {
            int ntile = unit >> 2, ks = unit & 3;
            int n = ntile * 16 + (lane & 15), k0 = ks * 32 + (lane >> 4) * 8;
            #pragma unroll
            for (int j = 0; j < 8; ++j) v[j] = f2bs(ldi(in.p[28], (size_t)(k0 + j) * 512 + n, f));
            *(s16x8*)(wT + W_W1T + ((size_t)unit * 64 + lane) * 8) = v;
        } else {
            int b2 = unit - 128;
            int ntile = b2 >> 4, ks = b2 & 15;
            int n = ntile * 16 + (lane & 15), k0 = ks * 32 + (lane >> 4) * 8;
            #pragma unroll
            for (int j = 0; j < 8; ++j) v[j] = f2bs(ldi(in.p[30], (size_t)(k0 + j) * 128 + n, f));
            *(s16x8*)(wT + W_W2T + ((size_t)b2 * 64 + lane) * 8) = v;
        }
    } else {
        int u = b - 133;
        int stage = u >> 4, pat = (u >> 2) & 3, h = u & 3;
        const void* rpb = in.p[stage ? 27 : 18];
        float* dst = BMT + (size_t)u * 2560;
        int er = pat >> 1, ec = pat & 1;
        for (int i = tid; i < 2560; i += 256) {
            float v = 0.f;
            int qp = i / 52, kp = i - qp * 52;
            if (qp < 49 && kp < 49) {
                int qpi = qp / 7, qpj = qp - qpi * 7, kpi = kp / 7, kpj = kp - kpi * 7;
                float bias = ldi(rpb, ((qpi - kpi + 6) * 13 + (qpj - kpj + 6)) * HEADS + h, f);
                int rq = (er ? (qpi < 4 ? 1 : 2) : 0) * 3 + (ec ? (qpj < 4 ? 1 : 2) : 0);
                int rk = (er ? (kpi < 4 ? 1 : 2) : 0) * 3 + (ec ? (kpj < 4 ? 1 : 2) : 0);
                v = (bias + (rq == rk ? 0.f : -100.f)) * LOG2E;
            }
            dst[i] = v;
        }
    }
}

// SA (per-channel tile, 49 rows): gather x (persist bf16 to xr) -> LN1 -> Q/K/V GEMM
// Q scaled by SCALE2 = SCALE*log2e (attn uses exp2)
__global__ __launch_bounds__(256) void k_qkv_sa(
    const void* __restrict__ x, bf16* __restrict__ xr,
    const float* __restrict__ P, const bf16* __restrict__ wT,
    const int* __restrict__ dflag,
    bf16* __restrict__ tokQ, bf16* __restrict__ tokK, bf16* __restrict__ tokV) {
    const int f = *dflag;
    __shared__ char ldsA[NPAD * SA];
    __shared__ int rowIdx[NROWS];
    __shared__ float gb[256];
    int wn = blockIdx.x, nc = blockIdx.y, tid = threadIdx.x;
    int t0 = nc * NROWS;
    if (tid < NROWS) rowIdx[tid] = tok_row(wn, t0 + tid);
    gb[tid] = tid < 128 ? P[P_G1 + tid] : P[P_N1B + tid - 128];
    for (int i = tid; i < 15 * SA / 4; i += 256) ((int*)(ldsA + NROWS * SA))[i] = 0;
    __syncthreads();
    for (int idx = tid; idx < NROWS * 16; idx += 256) {
        int t = idx >> 4, c8 = idx & 15;
        size_t g = (size_t)rowIdx[t] * Cn + c8 * 8;
        s16x8 v;
        if (f) {
            const float* s = (const float*)x + g;
            #pragma unroll
            for (int j = 0; j < 8; ++j) v[j] = f2bs(s[j]);
        } else {
            v = *(const s16x8*)((const bf16*)x + g);
        }
        *(s16x8*)(ldsA + t * SA + c8 * 16) = v;
        *(s16x8*)(xr + g) = v;
    }
    __syncthreads();
    if (tid < NROWS) ln_inplace(ldsA + tid * SA, gb);
    __syncthreads();
    int wv = tid >> 6, lane = tid & 63, l15 = lane & 15, lg = lane >> 4;
    #pragma unroll 1
    for (int mat = 0; mat < 3; ++mat) {
        const bf16* W = wT + mat * 16384;
        bf16* dst = mat == 0 ? tokQ : (mat == 1 ? tokK : tokV);
        #pragma unroll 1
        for (int ni = 0; ni < 2; ++ni) {
            int nt = wv * 2 + ni;
            f32x4 acc[4] = {};
            #pragma unroll
            for (int ks = 0; ks < 4; ++ks) {
                s16x8 bfrag = *(const s16x8*)(W + (((nt << 2) + ks) * 64 + lane) * 8);
                #pragma unroll
                for (int mt = 0; mt < 4; ++mt) {
                    s16x8 af = *(const s16x8*)(ldsA + (mt * 16 + l15) * SA + ks * 64 + lg * 16);
                    acc[mt] = MFMA(bfrag, af, acc[mt]);
                }
            }
            int col0 = nt * 16 + lg * 4;
            #pragma unroll
            for (int mt = 0; mt < 4; ++mt) {
                int tl = mt * 16 + l15;
                if (tl < NROWS) {
                    int t = t0 + tl;
                    s16x4 pk;
                    if (mat == 0) {
                        f32x4 b4 = *(const f32x4*)(P + P_QCSA + nc * 128 + col0);
                        #pragma unroll
                        for (int r = 0; r < 4; ++r) pk[r] = f2bs((acc[mt][r] + b4[r]) * SCALE2);
                    } else if (mat == 1) {
                        f32x4 b4 = *(const f32x4*)(P + P_KCSA + nc * 128 + col0);
                        #pragma unroll
                        for (int r = 0; r < 4; ++r) pk[r] = f2bs(acc[mt][r] + b4[r]);
                    } else {
                        f32x4 b4 = *(const f32x4*)(P + P_VCSA + col0);
                        #pragma unroll
                        for (int r = 0; r < 4; ++r) pk[r] = f2bs(acc[mt][r] + b4[r]);
                    }
                    *(s16x4*)(dst + ((size_t)wn * Tt + t) * Cn + col0) = pk;
                }
            }
        }
    }
}

// MFMA attention (4-wave): no-max exp2 softmax (Q and BM pre-scaled by log2e)
__global__ __launch_bounds__(256) void k_attn(
    const bf16* __restrict__ Q, const bf16* __restrict__ K, const bf16* __restrict__ V,
    bf16* __restrict__ O, const float* __restrict__ BMbase) {
    __shared__ char ldsK[40 * 256];
    __shared__ char ldsV[32 * 336];
    __shared__ char ldsP[4 * 16 * 336];
    __shared__ float BM[2560];
    __shared__ float lArr[4][16];
    int wn = blockIdx.x, h = blockIdx.y, tid = threadIdx.x;
    int wi = (wn >> 4) & 15, wj = wn & 15;
    size_t base = (size_t)wn * Tt * Cn + h * HDn;
    for (int idx = tid; idx < 640; idx += 256) {
        int key = idx >> 2, ch = idx & 3;
        s16x8 kv = {}, vv = {};
        if (key < Tt) {
            kv = *(const s16x8*)(K + base + (size_t)key * Cn + ch * 8);
            vv = *(const s16x8*)(V + base + (size_t)key * Cn + ch * 8);
        }
        *(s16x8*)(ldsK + (key >> 2) * 256 + (key & 3) * 64 + ch * 16) = kv;
        #pragma unroll
        for (int j = 0; j < 8; ++j)
            *(short*)(ldsV + (ch * 8 + j) * 336 + key * 2) = vv[j];
    }
    {
        int pat = ((wi == 15) << 1) | (wj == 15);
        const f32x4* src = (const f32x4*)(BMbase + (size_t)(pat * 4 + h) * 2560);
        f32x4* dst4 = (f32x4*)BM;
        for (int i = tid; i < 640; i += 256) dst4[i] = src[i];
    }
    __syncthreads();
    int wv = tid >> 6, lane = tid & 63, l15 = lane & 15, lg = lane >> 4;
    char* myP = ldsP + wv * (16 * 336);
    int kpA[10];
    #pragma unroll
    for (int nt = 0; nt < 10; ++nt) {
        int key = nt * 16 + l15;
        kpA[nt] = key - (key >= 147 ? 147 : (key >= 98 ? 98 : (key >= 49 ? 49 : 0)));
    }
    for (int mt = wv; mt < 10; mt += 4) {
        int qrow = mt * 16 + l15; if (qrow > 146) qrow = 146;
        s16x8 qf = *(const s16x8*)(Q + base + (size_t)qrow * Cn + lg * 8);
        f32x4 acc[10];
        #pragma unroll
        for (int nt = 0; nt < 10; ++nt) {
            int key = nt * 16 + l15;
            s16x8 bfrag = *(const s16x8*)(ldsK + (key >> 2) * 256 + (key & 3) * 64 + lg * 16);
            f32x4 z = {};
            acc[nt] = MFMA(qf, bfrag, z);
        }
        float linv[4];
        #pragma unroll
        for (int r = 0; r < 4; ++r) {
            int row = mt * 16 + lg * 4 + r;
            int qp = row - (row >= 147 ? 147 : (row >= 98 ? 98 : (row >= 49 ? 49 : 0)));
            float l = 0.f;
            #pragma unroll
            for (int nt = 0; nt < 10; ++nt) {
                float p = (nt == 9 && l15 >= 3) ? 0.f
                        : __builtin_amdgcn_exp2f(acc[nt][r] + BM[qp * 52 + kpA[nt]]);
                l += p;
                *(bf16*)(myP + (lg * 4 + r) * 336 + (nt * 16 + l15) * 2) = f2bf(p);
            }
            #pragma unroll
            for (int off = 1; off < 16; off <<= 1) l += __shfl_xor(l, off);
            linv[r] = 1.f / l;
        }
        if (l15 == 0) {
            #pragma unroll
            for (int r = 0; r < 4; ++r) lArr[wv][lg * 4 + r] = linv[r];
        }
        float myinv = lArr[wv][l15];
        #pragma unroll
        for (int ntv = 0; ntv < 2; ++ntv) {
            f32x4 ao = {};
            #pragma unroll
            for (int ks = 0; ks < 5; ++ks) {
                s16x8 af = *(const s16x8*)(myP + l15 * 336 + ks * 64 + lg * 16);
                s16x8 vf = *(const s16x8*)(ldsV + (ntv * 16 + l15) * 336 + ks * 64 + lg * 16);
                ao = MFMA(vf, af, ao);
            }
            int q = mt * 16 + l15;
            if (q < Tt) {
                s16x4 pk;
                #pragma unroll
                for (int r = 0; r < 4; ++r) pk[r] = f2bs(ao[r] * myinv);
                *(s16x4*)(O + base + (size_t)q * Cn + ntv * 16 + lg * 4) = pk;
            }
        }
    }
}

// CA output projection (per-channel tile): reg accumulators + early xr prefetch
__global__ __launch_bounds__(256) void k_proj(
    const bf16* __restrict__ tokO, const float* __restrict__ P, const bf16* __restrict__ W,
    int bpOff, bf16* __restrict__ xr) {
    __shared__ char ldsA[NPAD * SA];
    __shared__ int rowIdx[NROWS];
    int wn = blockIdx.x, nc = blockIdx.y, tid = threadIdx.x;
    int t0 = nc * NROWS;
    if (tid < NROWS) rowIdx[tid] = tok_row(wn, t0 + tid);
    for (int i = tid; i < 15 * SA / 4; i += 256) ((int*)(ldsA + NROWS * SA))[i] = 0;
    __syncthreads();
    int wv = tid >> 6, lane = tid & 63, l15 = lane & 15, lg = lane >> 4;
    s16x4 xrc[2][4];
    #pragma unroll
    for (int ni = 0; ni < 2; ++ni) {
        int col0 = (wv * 2 + ni) * 16 + lg * 4;
        #pragma unroll
        for (int mt = 0; mt < 4; ++mt) {
            int tl = mt * 16 + l15;
            int rr = rowIdx[tl < NROWS ? tl : 0];
            xrc[ni][mt] = *(const s16x4*)(xr + (size_t)rr * Cn + col0);
        }
    }
    for (int idx = tid; idx < NROWS * 16; idx += 256) {
        int t = idx >> 4, c8 = idx & 15;
        s16x8 v = *(const s16x8*)(tokO + ((size_t)wn * Tt + t0 + t) * Cn + c8 * 8);
        *(s16x8*)(ldsA + t * SA + c8 * 16) = v;
    }
    __syncthreads();
    f32x4 acc2[2][4] = {};
    #pragma unroll
    for (int ni = 0; ni < 2; ++ni) {
        int nt = wv * 2 + ni;
        #pragma unroll
        for (int ks = 0; ks < 4; ++ks) {
            s16x8 bfrag = *(const s16x8*)(W + (((nt << 2) + ks) * 64 + lane) * 8);
            #pragma unroll
            for (int mt = 0; mt < 4; ++mt) {
                s16x8 af = *(const s16x8*)(ldsA + (mt * 16 + l15) * SA + ks * 64 + lg * 16);
                acc2[ni][mt] = MFMA(bfrag, af, acc2[ni][mt]);
            }
        }
    }
    #pragma unroll
    for (int ni = 0; ni < 2; ++ni) {
        int col0 = (wv * 2 + ni) * 16 + lg * 4;
        f32x4 bp4 = *(const f32x4*)(P + bpOff + col0);
        #pragma unroll
        for (int mt = 0; mt < 4; ++mt) {
            int tl = mt * 16 + l15;
            if (tl < NROWS) {
                s16x4 pk;
                #pragma unroll
                for (int r = 0; r < 4; ++r) pk[r] = f2bs(bs2f(xrc[ni][mt][r]) + acc2[ni][mt][r] + bp4[r]);
                *(s16x4*)(xr + (size_t)rowIdx[tl] * Cn + col0) = pk;
            }
        }
    }
}

// Fused SA-proj + residual + LN2 + CA Q/K/V (per-channel tile); CA-Q uses SCALE2
__global__ __launch_bounds__(256) void k_proj_ca(
    const bf16* __restrict__ tokO, const float* __restrict__ P, const bf16* __restrict__ wT,
    const void* __restrict__ xkv, const int* __restrict__ dflag, bf16* __restrict__ xr,
    bf16* __restrict__ tokQ, bf16* __restrict__ tokK, bf16* __restrict__ tokV) {
    const int f = *dflag;
    __shared__ char ldsA[NPAD * SA];
    __shared__ int rowIdx[NROWS];
    __shared__ float gb[256];
    int wn = blockIdx.x, nc = blockIdx.y, tid = threadIdx.x;
    int t0 = nc * NROWS;
    if (tid < NROWS) rowIdx[tid] = tok_row(wn, t0 + tid);
    gb[tid] = tid < 128 ? P[P_G2 + tid] : P[P_N2B + tid - 128];
    for (int i = tid; i < 15 * SA / 4; i += 256) ((int*)(ldsA + NROWS * SA))[i] = 0;
    __syncthreads();
    for (int idx = tid; idx < NROWS * 16; idx += 256) {
        int t = idx >> 4, c8 = idx & 15;
        s16x8 v = *(const s16x8*)(tokO + ((size_t)wn * Tt + t0 + t) * Cn + c8 * 8);
        *(s16x8*)(ldsA + t * SA + c8 * 16) = v;
    }
    __syncthreads();
    int wv = tid >> 6, lane = tid & 63, l15 = lane & 15, lg = lane >> 4;
    {
        const bf16* W = wT + W_SAP;
        #pragma unroll 1
        for (int ni = 0; ni < 2; ++ni) {
            int nt = wv * 2 + ni;
            f32x4 acc[4] = {};
            #pragma unroll
            for (int ks = 0; ks < 4; ++ks) {
                s16x8 bfrag = *(const s16x8*)(W + (((nt << 2) + ks) * 64 + lane) * 8);
                #pragma unroll
                for (int mt = 0; mt < 4; ++mt) {
                    s16x8 af = *(const s16x8*)(ldsA + (mt * 16 + l15) * SA + ks * 64 + lg * 16);
                    acc[mt] = MFMA(bfrag, af, acc[mt]);
                }
            }
            int col0 = nt * 16 + lg * 4;
            f32x4 bp4 = *(const f32x4*)(P + P_BPSA + col0);
            #pragma unroll
            for (int mt = 0; mt < 4; ++mt) {
                int tl = mt * 16 + l15;
                if (tl < NROWS) {
                    size_t o = (size_t)rowIdx[tl] * Cn + col0;
                    s16x4 cur = *(const s16x4*)(xr + o);
                    s16x4 pk;
                    #pragma unroll
                    for (int r = 0; r < 4; ++r) pk[r] = f2bs(bs2f(cur[r]) + acc[mt][r] + bp4[r]);
                    *(s16x4*)(xr + o) = pk;
                }
            }
        }
    }
    __syncthreads();
    for (int idx = tid; idx < NROWS * 16; idx += 256) {
        int t = idx >> 4, c8 = idx & 15;
        s16x8 v = *(const s16x8*)(xr + (size_t)rowIdx[t] * Cn + c8 * 8);
        *(s16x8*)(ldsA + t * SA + c8 * 16) = v;
    }
    __syncthreads();
    if (tid < NROWS) ln_inplace(ldsA + tid * SA, gb);
    __syncthreads();
    {
        const bf16* W = wT + W_CAQ;
        #pragma unroll 1
        for (int ni = 0; ni < 2; ++ni) {
            int nt = wv * 2 + ni;
            f32x4 acc[4] = {};
            #pragma unroll
            for (int ks = 0; ks < 4; ++ks) {
                s16x8 bfrag = *(const s16x8*)(W + (((nt << 2) + ks) * 64 + lane) * 8);
                #pragma unroll
                for (int mt = 0; mt < 4; ++mt) {
                    s16x8 af = *(const s16x8*)(ldsA + (mt * 16 + l15) * SA + ks * 64 + lg * 16);
                    acc[mt] = MFMA(bfrag, af, acc[mt]);
                }
            }
            int col0 = nt * 16 + lg * 4;
            #pragma unroll
            for (int mt = 0; mt < 4; ++mt) {
                int tl = mt * 16 + l15;
                if (tl < NROWS) {
                    int t = t0 + tl;
                    f32x4 b4 = *(const f32x4*)(P + P_QCCA + nc * 128 + col0);
                    s16x4 pk;
                    #pragma unroll
                    for (int r = 0; r < 4; ++r) pk[r] = f2bs((acc[mt][r] + b4[r]) * SCALE2);
                    *(s16x4*)(tokQ + ((size_t)wn * Tt + t) * Cn + col0) = pk;
                }
            }
        }
    }
    __syncthreads();
    for (int idx = tid; idx < NROWS * 16; idx += 256) {
        int t = idx >> 4, c8 = idx & 15;
        s16x8 v;
        if (f) {
            const float* s = (const float*)xkv + (size_t)rowIdx[t] * Cn + c8 * 8;
            #pragma unroll
            for (int j = 0; j < 8; ++j) v[j] = f2bs(s[j]);
        } else {
            v = *(const s16x8*)((const bf16*)xkv + (size_t)rowIdx[t] * Cn + c8 * 8);
        }
        *(s16x8*)(ldsA + t * SA + c8 * 16) = v;
    }
    __syncthreads();
    #pragma unroll 1
    for (int mat = 0; mat < 2; ++mat) {
        const bf16* W = wT + (mat == 0 ? W_CAK : W_CAV);
        bf16* dst = mat == 0 ? tokK : tokV;
        #pragma unroll 1
        for (int ni = 0; ni < 2; ++ni) {
            int nt = wv * 2 + ni;
            f32x4 acc[4] = {};
            #pragma unroll
            for (int ks = 0; ks < 4; ++ks) {
                s16x8 bfrag = *(const s16x8*)(W + (((nt << 2) + ks) * 64 + lane) * 8);
                #pragma unroll
                for (int mt = 0; mt < 4; ++mt) {
                    s16x8 af = *(const s16x8*)(ldsA + (mt * 16 + l15) * SA + ks * 64 + lg * 16);
                    acc[mt] = MFMA(bfrag, af, acc[mt]);
                }
            }
            int col0 = nt * 16 + lg * 4;
            #pragma unroll
            for (int mt = 0; mt < 4; ++mt) {
                int tl = mt * 16 + l15;
                if (tl < NROWS) {
                    int t = t0 + tl;
                    f32x4 b4 = (mat == 0) ? *(const f32x4*)(P + P_KCCA + nc * 128 + col0)
                                          : *(const f32x4*)(P + P_VCCA + col0);
                    s16x4 pk;
                    #pragma unroll
                    for (int r = 0; r < 4; ++r) pk[r] = f2bs(acc[mt][r] + b4[r]);
                    *(s16x4*)(dst + ((size_t)wn * Tt + t) * Cn + col0) = pk;
                }
            }
        }
    }
}

// Fused LN3 + MLP: 32-token tile (33.8 KB LDS -> 4 blocks/CU), aliased LDS, rcp-GELU
__global__ __launch_bounds__(256) void k_mlp(
    const bf16* __restrict__ xr, const float* __restrict__ P, const bf16* __restrict__ wT,
    const int* __restrict__ dflag, void* __restrict__ outp) {
    __shared__ char ldsU[MT * SH];
    __shared__ float gb[256];
    char* ldsA = ldsU;
    char* ldsH = ldsU;
    int tid = threadIdx.x;
    size_t t0 = (size_t)blockIdx.x * MT;
    gb[tid] = tid < 128 ? P[P_G3 + tid] : P[P_N3B + tid - 128];
    __syncthreads();
    for (int idx = tid; idx < MT * 16; idx += 256) {
        int t = idx >> 4, c8 = idx & 15;
        s16x8 v = *(const s16x8*)(xr + (t0 + t) * Cn + c8 * 8);
        *(s16x8*)(ldsA + t * SA + c8 * 16) = v;
    }
    __syncthreads();
    {
        int row = tid >> 3, sub = tid & 7;
        if (sub < 4) ln_row4(ldsA + row * SA, gb, sub);
    }
    __syncthreads();
    int wv = tid >> 6, lane = tid & 63, l15 = lane & 15, lg = lane >> 4;
    const bf16* W1 = wT + W_W1T;
    s16x8 a[2][4];
    #pragma unroll
    for (int m = 0; m < 2; ++m)
        #pragma unroll
        for (int ks = 0; ks < 4; ++ks)
            a[m][ks] = *(const s16x8*)(ldsA + (m * 16 + l15) * SA + ks * 64 + lg * 16);
    __syncthreads();
    {
        int nt0 = wv * 8;
        s16x8 bc0 = *(const s16x8*)(W1 + (((nt0 << 2) + 0) * 64 + lane) * 8);
        s16x8 bc1 = *(const s16x8*)(W1 + (((nt0 << 2) + 1) * 64 + lane) * 8);
        s16x8 bc2 = *(const s16x8*)(W1 + (((nt0 << 2) + 2) * 64 + lane) * 8);
        s16x8 bc3 = *(const s16x8*)(W1 + (((nt0 << 2) + 3) * 64 + lane) * 8);
        #pragma unroll 1
        for (int ni = 0; ni < 8; ++ni) {
            int nt = nt0 + ni;
            s16x8 bn0 = *(const s16x8*)(W1 + ((((nt + 1) << 2) + 0) * 64 + lane) * 8);
            s16x8 bn1 = *(const s16x8*)(W1 + ((((nt + 1) << 2) + 1) * 64 + lane) * 8);
            s16x8 bn2 = *(const s16x8*)(W1 + ((((nt + 1) << 2) + 2) * 64 + lane) * 8);
            s16x8 bn3 = *(const s16x8*)(W1 + ((((nt + 1) << 2) + 3) * 64 + lane) * 8);
            f32x4 acc[2] = {};
            #pragma unroll
            for (int m = 0; m < 2; ++m) {
                acc[m] = MFMA(bc0, a[m][0], acc[m]);
                acc[m] = MFMA(bc1, a[m][1], acc[m]);
                acc[m] = MFMA(bc2, a[m][2], acc[m]);
                acc[m] = MFMA(bc3, a[m][3], acc[m]);
            }
            int col0 = nt * 16 + lg * 4;
            f32x4 b14 = *(const f32x4*)(P + P_B1 + col0);
            #pragma unroll
            for (int m = 0; m < 2; ++m) {
                s16x4 pk;
                #pragma unroll
                for (int r = 0; r < 4; ++r) pk[r] = f2bs(gelu(acc[m][r] + b14[r]));
                *(s16x4*)(ldsH + (m * 16 + l15) * SH + col0 * 2) = pk;
            }
            bc0 = bn0; bc1 = bn1; bc2 = bn2; bc3 = bn3;
        }
    }
    __syncthreads();
    const int f = *dflag;
    const bf16* W2 = wT + W_W2T;
    #pragma unroll 1
    for (int ni = 0; ni < 2; ++ni) {
        int nt = wv * 2 + ni;
        f32x4 acc[2] = {};
        s16x8 bc = *(const s16x8*)(W2 + (((nt << 4) + 0) * 64 + lane) * 8);
        #pragma unroll 1
        for (int ks = 0; ks < 16; ++ks) {
            s16x8 bn = *(const s16x8*)(W2 + (((nt << 4) + ks + 1) * 64 + lane) * 8);
            #pragma unroll
            for (int m = 0; m < 2; ++m) {
                s16x8 af = *(const s16x8*)(ldsH + (m * 16 + l15) * SH + ks * 64 + lg * 16);
                acc[m] = MFMA(bc, af, acc[m]);
            }
            bc = bn;
        }
        int col0 = nt * 16 + lg * 4;
        f32x4 b24 = *(const f32x4*)(P + P_B2 + col0);
        #pragma unroll
        for (int m = 0; m < 2; ++m) {
            size_t g = (t0 + m * 16 + l15) * Cn + col0;
            s16x4 cur = *(const s16x4*)(xr + g);
            if (f) {
                f32x4 o;
                #pragma unroll
                for (int r = 0; r < 4; ++r) o[r] = bs2f(cur[r]) + acc[m][r] + b24[r];
                *(f32x4*)((float*)outp + g) = o;
            } else {
                s16x4 pk;
                #pragma unroll
                for (int r = 0; r < 4; ++r) pk[r] = f2bs(bs2f(cur[r]) + acc[m][r] + b24[r]);
                *(s16x4*)((bf16*)outp + g) = pk;
            }
        }
    }
}

extern "C" void kernel_launch(void* const* d_in, const int* in_sizes, int n_in,
                              void* d_out, int out_size, void* d_ws, size_t ws_size,
                              hipStream_t stream) {
    Ptrs ptrs;
    for (int i = 0; i < 32; ++i) ptrs.p[i] = d_in[i];

    char* base = (char*)d_ws;
    float* P    = (float*)base;                   // 8192 f32 = 32 KB
    int*  dflag = (int*)(base + 32768);
    bf16* wT    = (bf16*)(base + 33024);          // 262144 bf16 = 512 KB
    float* BMT  = (float*)(wT + 262144);          // 32 * 2560 f32 = 327.7 KB
    bf16* xr    = (bf16*)(BMT + 81920);           // NE bf16 residual
    bf16* tokK  = xr + NE;
    bf16* tokV  = tokK + NE;
    bf16* tokQ  = (bf16*)d_out;                   // Q and O alias in d_out

    k_detect<<<1, 256, 0, stream>>>((const unsigned int*)d_in[0], dflag);
    k_prep<<<165, 256, 0, stream>>>(ptrs, dflag, P, wT, BMT);
    // ---- self-attention stage (also materializes xr = bf16(x)) ----
    k_qkv_sa<<<dim3(WNt, 3), 256, 0, stream>>>(d_in[0], xr, P, wT, dflag, tokQ, tokK, tokV);
    k_attn<<<dim3(WNt, HEADS), 256, 0, stream>>>(tokQ, tokK, tokV, tokQ, BMT);
    // ---- fused SA-proj + CA-qkv ----
    k_proj_ca<<<dim3(WNt, 3), 256, 0, stream>>>(tokQ, P, wT, d_in[1], dflag, xr, tokQ, tokK, tokV);
    // ---- cross-attention ----
    k_attn<<<dim3(WNt, HEADS), 256, 0, stream>>>(tokQ, tokK, tokV, tokQ, BMT + 16 * 2560);
    k_proj<<<dim3(WNt, 3), 256, 0, stream>>>(tokQ, P, wT + W_CAP, P_BPCA, xr);
    // ---- MLP stage ----
    k_mlp<<<(int)(NE / Cn / MT), 256, 0, stream>>>(xr, P, wT, dflag, d_out);
}